// Round 16
// baseline (54.265 us; speedup 1.0000x reference)
//
#include <hip/hip_runtime.h>

#define T_LEN  512
#define K_LEN  64
#define NFILT  32
#define NBATCH 64
#define XOFS2  64
#define XS2_SZ 384               // max idx = 64 + 319 = 383
#define SQRT_LOG2E 1.2011224087864498f
#define LN2        0.6931471805599453f

typedef __attribute__((ext_vector_type(2))) float f32x2;

// result[lane] = src[lane-1], lane0 -> 0 (DPP wave_shr:1, bound_ctrl=1)
static __device__ __forceinline__ float wave_shr1(float x) {
    int r = __builtin_amdgcn_update_dpp(0, __builtin_bit_cast(int, x),
                                        0x138, 0xF, 0xF, true);
    return __builtin_bit_cast(float, r);
}

static __device__ __forceinline__ f32x2 wave_shr1_x2(f32x2 v) {
    f32x2 r;
    r.x = wave_shr1(v.x);
    r.y = wave_shr1(v.y);
    return r;
}

template <int N>
static __device__ __forceinline__ float row_ror(float x) {
    int r = __builtin_amdgcn_update_dpp(0, __builtin_bit_cast(int, x),
                                        0x120 + N, 0xF, 0xF, true);
    return __builtin_bit_cast(float, r);
}

static __device__ __forceinline__ float exp2_fast(float x) {
#if __has_builtin(__builtin_amdgcn_exp2f)
    return __builtin_amdgcn_exp2f(x);
#else
    return exp2f(x);
#endif
}

// exact fp32 band interval for original column jj = j/63 (reference predicate)
static __device__ __forceinline__ void band_iv(float jj, int& lo, int& hi) {
    int a0 = 0, b0 = T_LEN - 1;
    while (a0 < b0) { int m = (a0 + b0) >> 1;
        if ((float)m / 511.0f - jj >= -0.2f) b0 = m; else a0 = m + 1; }
    lo = a0;
    a0 = 0; b0 = T_LEN - 1;
    while (a0 < b0) { int m = (a0 + b0 + 1) >> 1;
        if ((float)m / 511.0f - jj <= 0.2f) a0 = m; else b0 = m - 1; }
    hi = a0;
}

// BIDIRECTIONAL x 2-PROBLEMS: one wave handles problems (b,fA),(b,fB=fA+16),
// each split into fwd (rows 0..255) and bwd (rows 511..256, == fwd DP on
// reversed x/protos) half-chains: 4 independent 319-step chains per wave,
// packed as two f32x2 pairs (F = both problems' fwd, B = both bwd).
//   Z = sum_j Zf(255,j) * (Zb(256,j) + Zb(256,j+1))   [verified R15, absmax 0]
// 1024 waves = 1 wave/SIMD: per-step wall ~115cy is latency-set and invariant
// to per-step work (R3 vs R4, R12 vs R5/R13), so 4 chains ride free.
__global__ __launch_bounds__(256) void dtw_kernel(const float* __restrict__ x,
                                                  const float* __restrict__ protos,
                                                  float* __restrict__ out) {
    __shared__ f32x2 xs2[XS2_SZ];
    const int tid  = threadIdx.x;
    const int lane = tid & 63;
    const int wid  = tid >> 6;
    const int b    = blockIdx.x >> 2;               // 256 blocks: 4 per b
    const int fA   = ((blockIdx.x & 3) << 2) | wid; // 0..15
    const int fB   = fA + 16;

    // stage {x[i], x[511-i]} * sqrt(log2 e), zero-padded (shared: same b)
    for (int t0 = tid; t0 < XS2_SZ; t0 += 256) {
        int i = t0 - XOFS2;
        f32x2 v;
        bool ok = (i >= 0 && i < T_LEN);
        v.x = ok ? x[b * T_LEN + i] * SQRT_LOG2E : 0.0f;
        v.y = ok ? x[b * T_LEN + (T_LEN - 1) - i] * SQRT_LOG2E : 0.0f;
        xs2[t0] = v;
    }
    __syncthreads();

    const int jF = lane, jB = 63 - lane;            // original columns
    f32x2 pnF2, pnB2;                               // {probA, probB}
    pnF2.x = -protos[fA * K_LEN + jF] * SQRT_LOG2E;
    pnF2.y = -protos[fB * K_LEN + jF] * SQRT_LOG2E;
    pnB2.x = -protos[fA * K_LEN + jB] * SQRT_LOG2E;
    pnB2.y = -protos[fB * K_LEN + jB] * SQRT_LOG2E;

    int iloF, ihiF, iloB, ihiB;
    band_iv((float)jF / 63.0f, iloF, ihiF);
    band_iv((float)jB / 63.0f, iloB, ihiB);

    // fwd: original rows [iloF, min(ihiF,255)]
    const int loF = iloF, hiF = (ihiF < 255) ? ihiF : 255;
    // bwd: original rows [max(iloB,256), ihiB] -> reversed i_r = 511 - i
    const int loBo = (iloB > 256) ? iloB : 256;
    const int loB  = (T_LEN - 1) - ihiB;
    const int hiB  = (T_LEN - 1) - loBo;

    unsigned tF, rangeF, tB, rangeB;
    if (loF > hiF) { tF = 0x80000000u; rangeF = 0u; }
    else { tF = (unsigned)(-(lane + loF)); rangeF = (unsigned)(hiF - loF); }
    if (loB > hiB) { tB = 0x80000000u; rangeB = 0u; }
    else { tB = (unsigned)(-(lane + loB)); rangeB = (unsigned)(hiB - loB); }

    f32x2 prevF2 = {0.0f, 0.0f}, prevB2 = {0.0f, 0.0f};
    f32x2 capF2  = {0.0f, 0.0f}, capB2  = {0.0f, 0.0f};
    const float d0 = (lane == 0) ? 1.0f : 0.0f;     // Z(-1,-1) = 1 (all chains)
    f32x2 dgpF2 = {d0, d0}, dgpB2 = {d0, d0};
    int S2FA = 0, S2FB = 0, S2BA = 0, S2BB = 0;
    const int dcap = 255 + lane;                    // capture step (all chains)

    const f32x2* __restrict__ xp = &xs2[XOFS2 - lane];

    f32x2 A[32], Bv[32];
#pragma unroll
    for (int k = 0; k < 32; ++k) A[k] = xp[k];
    __builtin_amdgcn_sched_barrier(0);

#define STEP(XV, DCONST, CAPF) do {                           \
        f32x2 xv2_ = (XV);                                    \
        float selF_ = (tF <= rangeF) ? 0.0f : -3.0e38f; ++tF; \
        float selB_ = (tB <= rangeB) ? 0.0f : -3.0e38f; ++tB; \
        float dFA_ = xv2_.x + pnF2.x;                         \
        float dFB_ = xv2_.x + pnF2.y;                         \
        float dBA_ = xv2_.y + pnB2.x;                         \
        float dBB_ = xv2_.y + pnB2.y;                         \
        f32x2 wF_, wB_;                                       \
        wF_.x = exp2_fast(__builtin_fmaf(dFA_, -dFA_, selF_));\
        wF_.y = exp2_fast(__builtin_fmaf(dFB_, -dFB_, selF_));\
        wB_.x = exp2_fast(__builtin_fmaf(dBA_, -dBA_, selB_));\
        wB_.y = exp2_fast(__builtin_fmaf(dBB_, -dBB_, selB_));\
        f32x2 lF_ = wave_shr1_x2(prevF2);                     \
        f32x2 lB_ = wave_shr1_x2(prevB2);                     \
        f32x2 aF_ = prevF2 + dgpF2;                           \
        f32x2 aB_ = prevB2 + dgpB2;                           \
        f32x2 sF_ = aF_ + lF_;                                \
        f32x2 sB_ = aB_ + lB_;                                \
        dgpF2 = lF_; dgpB2 = lB_;                             \
        prevF2 = sF_ * wF_;                                   \
        prevB2 = sB_ * wB_;                                   \
        if (CAPF) {                                           \
            bool c_ = (dcap == (DCONST));                     \
            capF2.x = c_ ? prevF2.x : capF2.x;                \
            capF2.y = c_ ? prevF2.y : capF2.y;                \
            capB2.x = c_ ? prevB2.x : capB2.x;                \
            capB2.y = c_ ? prevB2.y : capB2.y;                \
        }                                                     \
    } while (0)

    // wave-uniform power-of-2 renorm per chain (Me = TGT - e), cadence 32
#define RENORM_CH(PV, DG, CP, S2, TGT) do {                                  \
        float m_ = PV;                                                       \
        m_ = fmaxf(m_, row_ror<8>(m_));                                      \
        m_ = fmaxf(m_, row_ror<4>(m_));                                      \
        m_ = fmaxf(m_, row_ror<2>(m_));                                      \
        m_ = fmaxf(m_, row_ror<1>(m_));                                      \
        int mi_ = __builtin_bit_cast(int, m_);                               \
        unsigned r0_ = (unsigned)__builtin_amdgcn_readlane(mi_, 0);          \
        unsigned r1_ = (unsigned)__builtin_amdgcn_readlane(mi_, 16);         \
        unsigned r2_ = (unsigned)__builtin_amdgcn_readlane(mi_, 32);         \
        unsigned r3_ = (unsigned)__builtin_amdgcn_readlane(mi_, 48);         \
        unsigned ra_ = r0_ > r1_ ? r0_ : r1_;                                \
        unsigned rb_ = r2_ > r3_ ? r2_ : r3_;                                \
        unsigned mx_ = ra_ > rb_ ? ra_ : rb_;                                \
        int e_  = (int)((mx_ >> 23) & 0xFF);                                 \
        int Me_ = (TGT) - e_;                                                \
        Me_ = Me_ < 1 ? 1 : (Me_ > 254 ? 254 : Me_);                         \
        float M_ = __builtin_bit_cast(float, Me_ << 23);                     \
        S2 += Me_ - 127;                                                     \
        PV *= M_;                                                            \
        DG *= M_;                                                            \
        CP *= M_;                                                            \
    } while (0)

#define RENORM() do {                                                        \
        RENORM_CH(prevF2.x, dgpF2.x, capF2.x, S2FA, 284);                    \
        RENORM_CH(prevF2.y, dgpF2.y, capF2.y, S2FB, 284);                    \
        RENORM_CH(prevB2.x, dgpB2.x, capB2.x, S2BA, 284);                    \
        RENORM_CH(prevB2.y, dgpB2.y, capB2.y, S2BB, 284);                    \
    } while (0)

    // chunk: prefetch next 32, run 32 steps, renorm
#define CHUNKRUN(CBASE, CUR, NXT, CAPF) do {                                 \
        _Pragma("unroll")                                                    \
        for (int k = 0; k < 32; ++k) NXT[k] = xp[(CBASE) + 32 + k];          \
        __builtin_amdgcn_sched_barrier(0);                                   \
        _Pragma("unroll")                                                    \
        for (int k = 0; k < 32; ++k) STEP(CUR[k], (CBASE) + k, CAPF);        \
        RENORM();                                                            \
        __builtin_amdgcn_sched_barrier(0);                                   \
    } while (0)

    CHUNKRUN(  0, A,  Bv, 0);
    CHUNKRUN( 32, Bv, A,  0);
    CHUNKRUN( 64, A,  Bv, 0);
    CHUNKRUN( 96, Bv, A,  0);
    CHUNKRUN(128, A,  Bv, 0);
    CHUNKRUN(160, Bv, A,  0);
    CHUNKRUN(192, A,  Bv, 0);
    CHUNKRUN(224, Bv, A,  1);    // step 255: lane 0 captures
    CHUNKRUN(256, A,  Bv, 1);    // steps 256..287: lanes 1..32
    // tail: steps 288..318 (31 steps), lanes 33..63 capture, no renorm
#pragma unroll
    for (int k = 0; k < 31; ++k) STEP(Bv[k], 288 + k, 1);

    // ---- epilogue: rescale caps to ~2^0, mirror bwd, combine, reduce ----
    RENORM_CH(capF2.x, dgpF2.x, prevF2.x, S2FA, 254);   // dummy extra args:
    RENORM_CH(capF2.y, dgpF2.y, prevF2.y, S2FB, 254);   // scaling dgp/prev
    RENORM_CH(capB2.x, dgpB2.x, prevB2.x, S2BA, 254);   // again is harmless
    RENORM_CH(capB2.y, dgpB2.y, prevB2.y, S2BB, 254);

    // lane j needs Zb(256, j), Zb(256, j+1); bwd column j lives at lane 63-j
    float cbjA  = __shfl(capB2.x, 63 - lane);
    float cbj1A = __shfl(capB2.x, 62 - lane);   // lane63: capF=0 kills it
    float cbjB  = __shfl(capB2.y, 63 - lane);
    float cbj1B = __shfl(capB2.y, 62 - lane);
    float sA = capF2.x * (cbjA + cbj1A);
    float sB = capF2.y * (cbjB + cbj1B);

    float mA = sA;
    mA += row_ror<8>(mA); mA += row_ror<4>(mA);
    mA += row_ror<2>(mA); mA += row_ror<1>(mA);
    int miA = __builtin_bit_cast(int, mA);
    float totA = mA;
    totA += __builtin_bit_cast(float, __builtin_amdgcn_readlane(miA, 0));
    totA += __builtin_bit_cast(float, __builtin_amdgcn_readlane(miA, 16));
    totA += __builtin_bit_cast(float, __builtin_amdgcn_readlane(miA, 32));

    float mB = sB;
    mB += row_ror<8>(mB); mB += row_ror<4>(mB);
    mB += row_ror<2>(mB); mB += row_ror<1>(mB);
    int miB = __builtin_bit_cast(int, mB);
    float totB = mB;
    totB += __builtin_bit_cast(float, __builtin_amdgcn_readlane(miB, 0));
    totB += __builtin_bit_cast(float, __builtin_amdgcn_readlane(miB, 16));
    totB += __builtin_bit_cast(float, __builtin_amdgcn_readlane(miB, 32));

    if (lane == 63) {
        float DA = ((float)(S2FA + S2BA) - log2f(totA)) * LN2;
        float DB = ((float)(S2FB + S2BB) - log2f(totB)) * LN2;
        out[b * NFILT + fA] = DA * (1.0f / (float)T_LEN);
        out[b * NFILT + fB] = DB * (1.0f / (float)T_LEN);
    }
#undef STEP
#undef RENORM_CH
#undef RENORM
#undef CHUNKRUN
}

extern "C" void kernel_launch(void* const* d_in, const int* in_sizes, int n_in,
                              void* d_out, int out_size, void* d_ws, size_t ws_size,
                              hipStream_t stream) {
    const float* x      = (const float*)d_in[0];
    const float* protos = (const float*)d_in[1];
    float* out          = (float*)d_out;

    dim3 grid(NBATCH * 4);   // 256 blocks x 4 waves = 1024 waves (1/SIMD)
    dim3 block(256);         // each wave: 2 problems x (fwd+bwd) = 4 chains
    hipLaunchKernelGGL(dtw_kernel, grid, block, 0, stream, x, protos, out);
}

// Round 17
// 36.216 us; speedup vs baseline: 1.4984x; 1.4984x over previous
//
#include <hip/hip_runtime.h>

#define T_LEN  512
#define K_LEN  64
#define NFILT  32
#define XOFS   64
#define XS_SZ  384               // max idx = 64 + 319 = 383
#define SQRT_LOG2E 1.2011224087864498f
#define LN2        0.6931471805599453f

// result[lane] = src[lane-1], lane0 -> 0 (DPP wave_shr:1, bound_ctrl=1)
static __device__ __forceinline__ float wave_shr1(float x) {
    int r = __builtin_amdgcn_update_dpp(0, __builtin_bit_cast(int, x),
                                        0x138, 0xF, 0xF, true);
    return __builtin_bit_cast(float, r);
}

template <int N>
static __device__ __forceinline__ float row_ror(float x) {
    int r = __builtin_amdgcn_update_dpp(0, __builtin_bit_cast(int, x),
                                        0x120 + N, 0xF, 0xF, true);
    return __builtin_bit_cast(float, r);
}

static __device__ __forceinline__ float exp2_fast(float x) {
#if __has_builtin(__builtin_amdgcn_exp2f)
    return __builtin_amdgcn_exp2f(x);
#else
    return exp2f(x);
#endif
}

// exact fp32 band interval for original column jj = j/63 (reference predicate)
static __device__ __forceinline__ void band_iv(float jj, int& lo, int& hi) {
    int a0 = 0, b0 = T_LEN - 1;
    while (a0 < b0) { int m = (a0 + b0) >> 1;
        if ((float)m / 511.0f - jj >= -0.2f) b0 = m; else a0 = m + 1; }
    lo = a0;
    a0 = 0; b0 = T_LEN - 1;
    while (a0 < b0) { int m = (a0 + b0 + 1) >> 1;
        if ((float)m / 511.0f - jj <= 0.2f) a0 = m; else b0 = m - 1; }
    hi = a0;
}

// BIDIRECTIONAL, ONE HALF-CHAIN PER WAVE: 2048 blocks x 2 waves = 4096 waves
// = 4 waves/SIMD (2x the TLP of any prior round; R7 proved separate waves
// overlap, R15/R16 proved packed chains don't). Per wave: minimal scalar
// 319-step DP. wave0 = fwd rows 0..255; wave1 = bwd rows 511..256 (== fwd DP
// on reversed x/protos).  Z = sum_j Zf(255,j) * (Zb(256,j) + Zb(256,j+1))
// [formula + band mapping hardware-validated in R15, absmax 0.0].
__global__ __launch_bounds__(128, 4) void dtw_kernel(const float* __restrict__ x,
                                                     const float* __restrict__ protos,
                                                     float* __restrict__ out) {
    __shared__ float xsF[XS_SZ];
    __shared__ float xsB[XS_SZ];
    __shared__ float capB_lds[65];
    __shared__ int   s2B_lds;
    const int tid  = threadIdx.x;
    const int lane = tid & 63;
    const int wid  = tid >> 6;                      // 0 = fwd, 1 = bwd
    const int b    = blockIdx.x >> 5;               // 2048 blocks: 32 per b
    const int f    = blockIdx.x & 31;

    // stage x (fwd order) and reversed x, * sqrt(log2 e); i in [0,319] valid
    for (int t0 = tid; t0 < XS_SZ; t0 += 128) {
        int i = t0 - XOFS;
        bool ok = (i >= 0);
        xsF[t0] = ok ? x[b * T_LEN + i] * SQRT_LOG2E : 0.0f;
        xsB[t0] = ok ? x[b * T_LEN + (T_LEN - 1) - i] * SQRT_LOG2E : 0.0f;
    }
    __syncthreads();

    // this wave's column in ORIGINAL coordinates
    const int col = wid ? (63 - lane) : lane;
    const float pn = -protos[f * K_LEN + col] * SQRT_LOG2E;

    int ilo, ihi;
    band_iv((float)col / 63.0f, ilo, ihi);
    int lo, hi;
    if (wid == 0) { lo = ilo; hi = (ihi < 255) ? ihi : 255; }
    else {
        int loBo = (ilo > 256) ? ilo : 256;         // original rows >= 256
        lo = (T_LEN - 1) - ihi;                     // reversed-row interval
        hi = (T_LEN - 1) - loBo;
    }
    unsigned t, range;
    if (lo > hi) { t = 0x80000000u; range = 0u; }
    else { t = (unsigned)(-(lane + lo)); range = (unsigned)(hi - lo); }

    float prev = 0.0f, cap = 0.0f;
    float dgp  = (lane == 0) ? 1.0f : 0.0f;         // Z(-1,-1) = 1
    int   S2   = 0;
    const int dcap = 255 + lane;                    // capture diagonal
    const float* __restrict__ xp = (wid ? xsB : xsF) + (XOFS - lane);

    float A[32], Bv[32];
#pragma unroll
    for (int k = 0; k < 32; ++k) A[k] = xp[k];
    __builtin_amdgcn_sched_barrier(0);

#define STEP(XV, DCONST, CAPF) do {                           \
        float xv_  = (XV);                                    \
        float sel_ = (t <= range) ? 0.0f : -3.0e38f;          \
        ++t;                                                  \
        float d_ = xv_ + pn;                                  \
        float w_ = exp2_fast(__builtin_fmaf(d_, -d_, sel_));  \
        float l_ = wave_shr1(prev);                           \
        float a_ = prev + dgp;                                \
        float s_ = a_ + l_;                                   \
        dgp  = l_;                                            \
        prev = s_ * w_;                                       \
        if (CAPF) cap = (dcap == (DCONST)) ? prev : cap;      \
    } while (0)

    // wave-uniform power-of-2 renorm of VAL's wave-max to ~2^(TGT-254)
#define RESCALE(VAL, TGT, APPLY) do {                                        \
        float m_ = VAL;                                                      \
        m_ = fmaxf(m_, row_ror<8>(m_));                                      \
        m_ = fmaxf(m_, row_ror<4>(m_));                                      \
        m_ = fmaxf(m_, row_ror<2>(m_));                                      \
        m_ = fmaxf(m_, row_ror<1>(m_));                                      \
        int mi_ = __builtin_bit_cast(int, m_);                               \
        unsigned r0_ = (unsigned)__builtin_amdgcn_readlane(mi_, 0);          \
        unsigned r1_ = (unsigned)__builtin_amdgcn_readlane(mi_, 16);         \
        unsigned r2_ = (unsigned)__builtin_amdgcn_readlane(mi_, 32);         \
        unsigned r3_ = (unsigned)__builtin_amdgcn_readlane(mi_, 48);         \
        unsigned ra_ = r0_ > r1_ ? r0_ : r1_;                                \
        unsigned rb_ = r2_ > r3_ ? r2_ : r3_;                                \
        unsigned mx_ = ra_ > rb_ ? ra_ : rb_;                                \
        int e_  = (int)((mx_ >> 23) & 0xFF);                                 \
        int Me_ = (TGT) - e_;                                                \
        Me_ = Me_ < 1 ? 1 : (Me_ > 254 ? 254 : Me_);                         \
        float M_ = __builtin_bit_cast(float, Me_ << 23);                     \
        S2 += Me_ - 127;                                                     \
        APPLY;                                                               \
    } while (0)

#define RENORM() RESCALE(prev, 284, { prev *= M_; dgp *= M_; cap *= M_; })

#define CHUNKRUN(CBASE, CUR, NXT, CAPF) do {                                 \
        _Pragma("unroll")                                                    \
        for (int k = 0; k < 32; ++k) NXT[k] = xp[(CBASE) + 32 + k];          \
        __builtin_amdgcn_sched_barrier(0);                                   \
        _Pragma("unroll")                                                    \
        for (int k = 0; k < 32; ++k) STEP(CUR[k], (CBASE) + k, CAPF);        \
        RENORM();                                                            \
        __builtin_amdgcn_sched_barrier(0);                                   \
    } while (0)

    CHUNKRUN(  0, A,  Bv, 0);
    CHUNKRUN( 32, Bv, A,  0);
    CHUNKRUN( 64, A,  Bv, 0);
    CHUNKRUN( 96, Bv, A,  0);
    CHUNKRUN(128, A,  Bv, 0);
    CHUNKRUN(160, Bv, A,  0);
    CHUNKRUN(192, A,  Bv, 0);
    CHUNKRUN(224, Bv, A,  1);    // d=255: lane 0 captures
    CHUNKRUN(256, A,  Bv, 1);    // d=256..287: lanes 1..32
    // tail: d = 288..318 (31 steps), lanes 33..63 capture, no renorm
#pragma unroll
    for (int k = 0; k < 31; ++k) STEP(Bv[k], 288 + k, 1);

    // rescale cap so wave-max ~ 2^0 (bounded products in the combine)
    RESCALE(cap, 254, { cap *= M_; });

    // exchange: bwd wave publishes cap (mirrored to original columns) + S2
    if (wid == 1) {
        capB_lds[63 - lane] = cap;      // reversed col lane -> orig col 63-lane
        if (lane == 0) { capB_lds[64] = 0.0f; s2B_lds = S2; }
    }
    __syncthreads();

    if (wid == 0) {
        float cb0 = capB_lds[lane];
        float cb1 = capB_lds[lane + 1];
        float s = cap * (cb0 + cb1);    // Zf(255,j) * (Zb(256,j)+Zb(256,j+1))
        float m = s;
        m += row_ror<8>(m);
        m += row_ror<4>(m);
        m += row_ror<2>(m);
        m += row_ror<1>(m);
        int mi = __builtin_bit_cast(int, m);
        float tot = m;                  // correct on lanes 48..63
        tot += __builtin_bit_cast(float, __builtin_amdgcn_readlane(mi, 0));
        tot += __builtin_bit_cast(float, __builtin_amdgcn_readlane(mi, 16));
        tot += __builtin_bit_cast(float, __builtin_amdgcn_readlane(mi, 32));
        if (lane == 63) {
            float D = ((float)(S2 + s2B_lds) - log2f(tot)) * LN2;
            out[b * NFILT + f] = D * (1.0f / (float)T_LEN);
        }
    }
#undef STEP
#undef RESCALE
#undef RENORM
#undef CHUNKRUN
}

extern "C" void kernel_launch(void* const* d_in, const int* in_sizes, int n_in,
                              void* d_out, int out_size, void* d_ws, size_t ws_size,
                              hipStream_t stream) {
    const float* x      = (const float*)d_in[0];
    const float* protos = (const float*)d_in[1];
    float* out          = (float*)d_out;

    dim3 grid(64 * 32);      // 2048 blocks x 2 waves = 4096 waves = 4/SIMD
    dim3 block(128);         // wave0 = fwd half, wave1 = bwd half of one (b,f)
    hipLaunchKernelGGL(dtw_kernel, grid, block, 0, stream, x, protos, out);
}

// Round 18
// 29.279 us; speedup vs baseline: 1.8534x; 1.2369x over previous
//
#include <hip/hip_runtime.h>

#define T_LEN  512
#define K_LEN  64
#define NFILT  32
#define XOFS   64
#define XS_SZ  384               // max idx = 64 + 319 = 383
#define SQRT_LOG2E 1.2011224087864498f
#define LN2        0.6931471805599453f

typedef __attribute__((ext_vector_type(2))) float f32x2;

// result[lane] = src[lane-1], lane0 -> 0 (DPP wave_shr:1, bound_ctrl=1)
static __device__ __forceinline__ float wave_shr1(float x) {
    int r = __builtin_amdgcn_update_dpp(0, __builtin_bit_cast(int, x),
                                        0x138, 0xF, 0xF, true);
    return __builtin_bit_cast(float, r);
}

static __device__ __forceinline__ f32x2 wave_shr1_x2(f32x2 v) {
    f32x2 r;
    r.x = wave_shr1(v.x);
    r.y = wave_shr1(v.y);
    return r;
}

template <int N>
static __device__ __forceinline__ float row_ror(float x) {
    int r = __builtin_amdgcn_update_dpp(0, __builtin_bit_cast(int, x),
                                        0x120 + N, 0xF, 0xF, true);
    return __builtin_bit_cast(float, r);
}

static __device__ __forceinline__ float exp2_fast(float x) {
#if __has_builtin(__builtin_amdgcn_exp2f)
    return __builtin_amdgcn_exp2f(x);
#else
    return exp2f(x);
#endif
}

// exact fp32 band interval for original column jj = j/63 (reference predicate)
static __device__ __forceinline__ void band_iv(float jj, int& lo, int& hi) {
    int a0 = 0, b0 = T_LEN - 1;
    while (a0 < b0) { int m = (a0 + b0) >> 1;
        if ((float)m / 511.0f - jj >= -0.2f) b0 = m; else a0 = m + 1; }
    lo = a0;
    a0 = 0; b0 = T_LEN - 1;
    while (a0 < b0) { int m = (a0 + b0 + 1) >> 1;
        if ((float)m / 511.0f - jj <= 0.2f) a0 = m; else b0 = m - 1; }
    hi = a0;
}

// BIDIRECTIONAL wave-split (R17, validated) x 2-PROBLEM packing (R12,
// validated): each wave runs ONE direction for TWO problems (fA, fB=fA+16;
// same b) -- shared x scalar, shared band/sel, R12's cheap packed step --
// over 319 anti-diagonals. 1024 pairs x 2 dir-waves = 2048 waves = 2/SIMD.
//   Z = sum_j Zf(255,j) * (Zb(256,j) + Zb(256,j+1))
__global__ __launch_bounds__(256) void dtw_kernel(const float* __restrict__ x,
                                                  const float* __restrict__ protos,
                                                  float* __restrict__ out) {
    __shared__ float xsF[XS_SZ];
    __shared__ float xsB[XS_SZ];
    __shared__ f32x2 capB_lds[2][65];
    __shared__ int   s2B_lds[2][2];
    const int tid  = threadIdx.x;
    const int lane = tid & 63;
    const int wid  = tid >> 6;                      // 4 waves/block
    const int pairI = wid >> 1;                     // 2 problem-pairs/block
    const int dirW  = wid & 1;                      // 0 = fwd, 1 = bwd
    const int b    = blockIdx.x >> 3;               // 512 blocks: 8 per b
    const int fA   = ((blockIdx.x & 7) << 1) | pairI;  // 0..15
    const int fB   = fA + 16;

    // stage x fwd + reversed, * sqrt(log2 e); valid i in [0, 319]
    for (int t0 = tid; t0 < XS_SZ; t0 += 256) {
        int i = t0 - XOFS;
        bool ok = (i >= 0);
        xsF[t0] = ok ? x[b * T_LEN + i] * SQRT_LOG2E : 0.0f;
        xsB[t0] = ok ? x[b * T_LEN + (T_LEN - 1) - i] * SQRT_LOG2E : 0.0f;
    }
    __syncthreads();

    // this wave's column in ORIGINAL coordinates (same map for both problems)
    const int col = dirW ? (63 - lane) : lane;
    f32x2 pn2;
    pn2.x = -protos[fA * K_LEN + col] * SQRT_LOG2E;
    pn2.y = -protos[fB * K_LEN + col] * SQRT_LOG2E;

    int ilo, ihi;
    band_iv((float)col / 63.0f, ilo, ihi);
    int lo, hi;
    if (dirW == 0) { lo = ilo; hi = (ihi < 255) ? ihi : 255; }
    else {
        int loBo = (ilo > 256) ? ilo : 256;         // original rows >= 256
        lo = (T_LEN - 1) - ihi;                     // reversed-row interval
        hi = (T_LEN - 1) - loBo;
    }
    unsigned t, range;
    if (lo > hi) { t = 0x80000000u; range = 0u; }
    else { t = (unsigned)(-(lane + lo)); range = (unsigned)(hi - lo); }

    f32x2 prev2 = {0.0f, 0.0f}, cap2 = {0.0f, 0.0f};
    const float d0 = (lane == 0) ? 1.0f : 0.0f;     // Z(-1,-1) = 1
    f32x2 dgp2 = {d0, d0};
    int S2A = 0, S2B = 0;
    const int dcap = 255 + lane;                    // capture diagonal
    const float* __restrict__ xp = (dirW ? xsB : xsF) + (XOFS - lane);

    float A[32], Bv[32];
#pragma unroll
    for (int k = 0; k < 32; ++k) A[k] = xp[k];
    __builtin_amdgcn_sched_barrier(0);

#define STEP(XV, DCONST, CAPF) do {                           \
        float xv_  = (XV);                                    \
        float sel_ = (t <= range) ? 0.0f : -3.0e38f;          \
        ++t;                                                  \
        float dA_ = xv_ + pn2.x;                              \
        float dB_ = xv_ + pn2.y;                              \
        f32x2 w2_;                                            \
        w2_.x = exp2_fast(__builtin_fmaf(dA_, -dA_, sel_));   \
        w2_.y = exp2_fast(__builtin_fmaf(dB_, -dB_, sel_));   \
        f32x2 l2_ = wave_shr1_x2(prev2);                      \
        f32x2 a2_ = prev2 + dgp2;                             \
        f32x2 s2_ = a2_ + l2_;                                \
        dgp2  = l2_;                                          \
        prev2 = s2_ * w2_;                                    \
        if (CAPF) {                                           \
            bool c_ = (dcap == (DCONST));                     \
            cap2.x = c_ ? prev2.x : cap2.x;                   \
            cap2.y = c_ ? prev2.y : cap2.y;                   \
        }                                                     \
    } while (0)

    // wave-uniform power-of-2 renorm per chain (Me = TGT - e)
#define RESCALE_CH(PV, DG, CP, S2, TGT) do {                                 \
        float m_ = PV;                                                       \
        m_ = fmaxf(m_, row_ror<8>(m_));                                      \
        m_ = fmaxf(m_, row_ror<4>(m_));                                      \
        m_ = fmaxf(m_, row_ror<2>(m_));                                      \
        m_ = fmaxf(m_, row_ror<1>(m_));                                      \
        int mi_ = __builtin_bit_cast(int, m_);                               \
        unsigned r0_ = (unsigned)__builtin_amdgcn_readlane(mi_, 0);          \
        unsigned r1_ = (unsigned)__builtin_amdgcn_readlane(mi_, 16);         \
        unsigned r2_ = (unsigned)__builtin_amdgcn_readlane(mi_, 32);         \
        unsigned r3_ = (unsigned)__builtin_amdgcn_readlane(mi_, 48);         \
        unsigned ra_ = r0_ > r1_ ? r0_ : r1_;                                \
        unsigned rb_ = r2_ > r3_ ? r2_ : r3_;                                \
        unsigned mx_ = ra_ > rb_ ? ra_ : rb_;                                \
        int e_  = (int)((mx_ >> 23) & 0xFF);                                 \
        int Me_ = (TGT) - e_;                                                \
        Me_ = Me_ < 1 ? 1 : (Me_ > 254 ? 254 : Me_);                         \
        float M_ = __builtin_bit_cast(float, Me_ << 23);                     \
        S2 += Me_ - 127;                                                     \
        PV *= M_;                                                            \
        DG *= M_;                                                            \
        CP *= M_;                                                            \
    } while (0)

#define RENORM() do {                                                        \
        RESCALE_CH(prev2.x, dgp2.x, cap2.x, S2A, 284);                       \
        RESCALE_CH(prev2.y, dgp2.y, cap2.y, S2B, 284);                       \
    } while (0)

#define CHUNKRUN(CBASE, CUR, NXT, CAPF) do {                                 \
        _Pragma("unroll")                                                    \
        for (int k = 0; k < 32; ++k) NXT[k] = xp[(CBASE) + 32 + k];          \
        __builtin_amdgcn_sched_barrier(0);                                   \
        _Pragma("unroll")                                                    \
        for (int k = 0; k < 32; ++k) STEP(CUR[k], (CBASE) + k, CAPF);        \
        RENORM();                                                            \
        __builtin_amdgcn_sched_barrier(0);                                   \
    } while (0)

    CHUNKRUN(  0, A,  Bv, 0);
    CHUNKRUN( 32, Bv, A,  0);
    CHUNKRUN( 64, A,  Bv, 0);
    CHUNKRUN( 96, Bv, A,  0);
    CHUNKRUN(128, A,  Bv, 0);
    CHUNKRUN(160, Bv, A,  0);
    CHUNKRUN(192, A,  Bv, 0);
    CHUNKRUN(224, Bv, A,  1);    // d=255: lane 0 captures
    CHUNKRUN(256, A,  Bv, 1);    // d=256..287: lanes 1..32
    // tail: d = 288..318 (31 steps), lanes 33..63 capture, no renorm
#pragma unroll
    for (int k = 0; k < 31; ++k) STEP(Bv[k], 288 + k, 1);

    // rescale caps so each chain's wave-max ~ 2^0 (bounded combine products);
    // prev/dgp are dead - scaling them too is harmless.
    RESCALE_CH(cap2.x, dgp2.x, prev2.x, S2A, 254);
    RESCALE_CH(cap2.y, dgp2.y, prev2.y, S2B, 254);

    // exchange: bwd wave publishes mirrored caps + S2s for its pair
    if (dirW == 1) {
        capB_lds[pairI][63 - lane] = cap2;   // reversed col -> orig col
        if (lane == 0) {
            f32x2 z = {0.0f, 0.0f};
            capB_lds[pairI][64] = z;
            s2B_lds[pairI][0] = S2A;
            s2B_lds[pairI][1] = S2B;
        }
    }
    __syncthreads();

    if (dirW == 0) {
        f32x2 cb0 = capB_lds[pairI][lane];
        f32x2 cb1 = capB_lds[pairI][lane + 1];
        float sA = cap2.x * (cb0.x + cb1.x);  // Zf(255,j)*(Zb(256,j)+Zb(256,j+1))
        float sB = cap2.y * (cb0.y + cb1.y);

        float mA = sA;
        mA += row_ror<8>(mA); mA += row_ror<4>(mA);
        mA += row_ror<2>(mA); mA += row_ror<1>(mA);
        int miA = __builtin_bit_cast(int, mA);
        float totA = mA;                      // correct on lanes 48..63
        totA += __builtin_bit_cast(float, __builtin_amdgcn_readlane(miA, 0));
        totA += __builtin_bit_cast(float, __builtin_amdgcn_readlane(miA, 16));
        totA += __builtin_bit_cast(float, __builtin_amdgcn_readlane(miA, 32));

        float mB = sB;
        mB += row_ror<8>(mB); mB += row_ror<4>(mB);
        mB += row_ror<2>(mB); mB += row_ror<1>(mB);
        int miB = __builtin_bit_cast(int, mB);
        float totB = mB;
        totB += __builtin_bit_cast(float, __builtin_amdgcn_readlane(miB, 0));
        totB += __builtin_bit_cast(float, __builtin_amdgcn_readlane(miB, 16));
        totB += __builtin_bit_cast(float, __builtin_amdgcn_readlane(miB, 32));

        if (lane == 63) {
            float DA = ((float)(S2A + s2B_lds[pairI][0]) - log2f(totA)) * LN2;
            float DB = ((float)(S2B + s2B_lds[pairI][1]) - log2f(totB)) * LN2;
            out[b * NFILT + fA] = DA * (1.0f / (float)T_LEN);
            out[b * NFILT + fB] = DB * (1.0f / (float)T_LEN);
        }
    }
#undef STEP
#undef RESCALE_CH
#undef RENORM
#undef CHUNKRUN
}

extern "C" void kernel_launch(void* const* d_in, const int* in_sizes, int n_in,
                              void* d_out, int out_size, void* d_ws, size_t ws_size,
                              hipStream_t stream) {
    const float* x      = (const float*)d_in[0];
    const float* protos = (const float*)d_in[1];
    float* out          = (float*)d_out;

    dim3 grid(64 * 8);       // 512 blocks x 4 waves = 2048 waves = 2/SIMD
    dim3 block(256);         // wave = one direction x two problems
    hipLaunchKernelGGL(dtw_kernel, grid, block, 0, stream, x, protos, out);
}

// Round 19
// 27.590 us; speedup vs baseline: 1.9668x; 1.0612x over previous
//
#include <hip/hip_runtime.h>

#define T_LEN  512
#define K_LEN  64
#define NFILT  32
#define NBATCH 64
#define XOFS   64                // pad: min element index = XOFS-63 >= 1
#define XS_SZ  640               // max element index read = 639
#define CHUNK  32
#define SQRT_LOG2E 1.2011224087864498f
#define LN2        0.6931471805599453f

typedef __attribute__((ext_vector_type(2))) float f32x2;

// result[lane] = src[lane-1], lane0 -> 0 (DPP wave_shr:1, bound_ctrl=1)
static __device__ __forceinline__ float wave_shr1(float x) {
    int r = __builtin_amdgcn_update_dpp(0, __builtin_bit_cast(int, x),
                                        0x138, 0xF, 0xF, true);
    return __builtin_bit_cast(float, r);
}

static __device__ __forceinline__ f32x2 wave_shr1_x2(f32x2 v) {
    f32x2 r;
    r.x = wave_shr1(v.x);
    r.y = wave_shr1(v.y);
    return r;
}

template <int N>
static __device__ __forceinline__ float row_ror(float x) {
    int r = __builtin_amdgcn_update_dpp(0, __builtin_bit_cast(int, x),
                                        0x120 + N, 0xF, 0xF, true);
    return __builtin_bit_cast(float, r);
}

static __device__ __forceinline__ float exp2_fast(float x) {
#if __has_builtin(__builtin_amdgcn_exp2f)
    return __builtin_amdgcn_exp2f(x);
#else
    return exp2f(x);
#endif
}

// Linear-domain band-limited soft-DTW, 2 problems/wave (f, f+16; same b),
// 1024 waves. Z = 2^S2 * exp(-D);
// Z[i,j] = exp(-C[i,j]) * (Z[i-1,j] + Z[i,j-1] + Z[i-1,j-1]).
// CHAMPION (R12, 27.485 us, absmax 0.0): packed-f32 state (v_pk_add/mul),
// xs PRE-SCALED by sqrt(log2 e) so d = xv + pn (pn = -p*s); band mask folded
// into the exp argument as exact 0; wave-uniform 2^30-target renorm each
// 32-step chunk. Design-matrix rounds R5-R18 confirmed every structural
// alternative (phase-split, fused pipeline, DPP hoist, rolled loop,
// bidirectional bisection, TLP 2-4 waves/SIMD) is equal or worse.
__global__ __launch_bounds__(256) void dtw_kernel(const float* __restrict__ x,
                                                  const float* __restrict__ protos,
                                                  float* __restrict__ out) {
    __shared__ float xs[XS_SZ];
    const int tid  = threadIdx.x;
    const int lane = tid & 63;
    const int wid  = tid >> 6;
    const int b    = blockIdx.x >> 2;               // 256 blocks: 4 per b
    const int fA   = ((blockIdx.x & 3) << 2) | wid; // 0..15
    const int fB   = fA + 16;

    for (int t0 = tid; t0 < XS_SZ; t0 += 256) {
        int i = t0 - XOFS;
        xs[t0] = (i >= 0 && i < T_LEN) ? x[b * T_LEN + i] * SQRT_LOG2E : 0.0f;
    }
    __syncthreads();

    const float pAn = -protos[fA * K_LEN + lane] * SQRT_LOG2E;
    const float pBn = -protos[fB * K_LEN + lane] * SQRT_LOG2E;
    const float jj  = (float)lane / 63.0f;

    // exact fp32 band interval per column (same predicate as reference)
    int a0 = 0, b0 = T_LEN - 1;
    while (a0 < b0) { int m = (a0 + b0) >> 1;
        if ((float)m / 511.0f - jj >= -0.2f) b0 = m; else a0 = m + 1; }
    const int ilo = a0;
    a0 = 0; b0 = T_LEN - 1;
    while (a0 < b0) { int m = (a0 + b0 + 1) >> 1;
        if ((float)m / 511.0f - jj <= 0.2f) a0 = m; else b0 = m - 1; }
    const int ihi = a0;

    const unsigned range = (unsigned)(ihi - ilo);
    unsigned t = (unsigned)(-(lane + ilo));
    f32x2 prev2 = {0.0f, 0.0f};
    const float d0 = (lane == 0) ? 1.0f : 0.0f;     // Z[-1,-1] = 1
    f32x2 dgp2 = {d0, d0};
    int   S2A = 0, S2B = 0;
    int   base = XOFS - lane;

    float A[CHUNK], Bv[CHUNK];
#pragma unroll
    for (int k = 0; k < CHUNK; ++k) A[k] = xs[base + k];
    __builtin_amdgcn_sched_barrier(0);

    // band mask folded into exp arg: out-of-band -> exp2(-3e38) == 0 exactly
#define STEP(XV) do {                                         \
        float xv_  = (XV);                                    \
        float sel_ = (t <= range) ? 0.0f : -3.0e38f;          \
        ++t;                                                  \
        float dA_ = xv_ + pAn;   /* xv pre-scaled; pn=-p*s */ \
        float dB_ = xv_ + pBn;                                \
        f32x2 w2_;                                            \
        w2_.x = exp2_fast(__builtin_fmaf(dA_, -dA_, sel_));   \
        w2_.y = exp2_fast(__builtin_fmaf(dB_, -dB_, sel_));   \
        f32x2 l2_ = wave_shr1_x2(prev2);                      \
        f32x2 a2_ = prev2 + dgp2;      /* v_pk_add_f32 */     \
        f32x2 s2_ = a2_ + l2_;         /* v_pk_add_f32 */     \
        dgp2  = l2_;                                          \
        prev2 = s2_ * w2_;             /* v_pk_mul_f32 */     \
    } while (0)

    // wave-uniform power-of-2 renorm to max ~ 2^30 (Me = 284-e), cadence 32;
    // per-problem M computed scalar, applied packed.
#define RENORM() do {                                                        \
        float MA_, MB_;                                                      \
        {                                                                    \
            float m_ = prev2.x;                                              \
            m_ = fmaxf(m_, row_ror<8>(m_));                                  \
            m_ = fmaxf(m_, row_ror<4>(m_));                                  \
            m_ = fmaxf(m_, row_ror<2>(m_));                                  \
            m_ = fmaxf(m_, row_ror<1>(m_));                                  \
            int mi_ = __builtin_bit_cast(int, m_);                           \
            unsigned r0_ = (unsigned)__builtin_amdgcn_readlane(mi_, 0);      \
            unsigned r1_ = (unsigned)__builtin_amdgcn_readlane(mi_, 16);     \
            unsigned r2_ = (unsigned)__builtin_amdgcn_readlane(mi_, 32);     \
            unsigned r3_ = (unsigned)__builtin_amdgcn_readlane(mi_, 48);     \
            unsigned ra_ = r0_ > r1_ ? r0_ : r1_;                            \
            unsigned rb_ = r2_ > r3_ ? r2_ : r3_;                            \
            unsigned mx_ = ra_ > rb_ ? ra_ : rb_;                            \
            int e_  = (int)((mx_ >> 23) & 0xFF);                             \
            int Me_ = 284 - e_;                                              \
            Me_ = Me_ < 1 ? 1 : (Me_ > 254 ? 254 : Me_);                     \
            MA_ = __builtin_bit_cast(float, Me_ << 23);                      \
            S2A += Me_ - 127;                                                \
        }                                                                    \
        {                                                                    \
            float m_ = prev2.y;                                              \
            m_ = fmaxf(m_, row_ror<8>(m_));                                  \
            m_ = fmaxf(m_, row_ror<4>(m_));                                  \
            m_ = fmaxf(m_, row_ror<2>(m_));                                  \
            m_ = fmaxf(m_, row_ror<1>(m_));                                  \
            int mi_ = __builtin_bit_cast(int, m_);                           \
            unsigned r0_ = (unsigned)__builtin_amdgcn_readlane(mi_, 0);      \
            unsigned r1_ = (unsigned)__builtin_amdgcn_readlane(mi_, 16);     \
            unsigned r2_ = (unsigned)__builtin_amdgcn_readlane(mi_, 32);     \
            unsigned r3_ = (unsigned)__builtin_amdgcn_readlane(mi_, 48);     \
            unsigned ra_ = r0_ > r1_ ? r0_ : r1_;                            \
            unsigned rb_ = r2_ > r3_ ? r2_ : r3_;                            \
            unsigned mx_ = ra_ > rb_ ? ra_ : rb_;                            \
            int e_  = (int)((mx_ >> 23) & 0xFF);                             \
            int Me_ = 284 - e_;                                              \
            Me_ = Me_ < 1 ? 1 : (Me_ > 254 ? 254 : Me_);                     \
            MB_ = __builtin_bit_cast(float, Me_ << 23);                      \
            S2B += Me_ - 127;                                                \
        }                                                                    \
        f32x2 M2_ = {MA_, MB_};                                              \
        prev2 = prev2 * M2_;           /* v_pk_mul_f32 */                    \
        dgp2  = dgp2  * M2_;           /* v_pk_mul_f32 */                    \
    } while (0)

#pragma unroll 1
    for (int cc = 0; cc < 8; ++cc) {
        // prefetch next chunk into Bv, pinned BEFORE this chunk's compute
#pragma unroll
        for (int k = 0; k < CHUNK; ++k) Bv[k] = xs[base + CHUNK + k];
        __builtin_amdgcn_sched_barrier(0);
#pragma unroll
        for (int k = 0; k < CHUNK; ++k) STEP(A[k]);
        RENORM();
        __builtin_amdgcn_sched_barrier(0);
        base += CHUNK;
        // prefetch next chunk into A, pinned BEFORE this chunk's compute
#pragma unroll
        for (int k = 0; k < CHUNK; ++k) A[k] = xs[base + CHUNK + k];
        __builtin_amdgcn_sched_barrier(0);
#pragma unroll
        for (int k = 0; k < CHUNK; ++k) STEP(Bv[k]);
        RENORM();
        __builtin_amdgcn_sched_barrier(0);
        base += CHUNK;
    }
    // steps 512..543 with A; prefetch tail (544..574 + pad) into Bv
#pragma unroll
    for (int k = 0; k < CHUNK; ++k) Bv[k] = xs[base + CHUNK + k];
    __builtin_amdgcn_sched_barrier(0);
#pragma unroll
    for (int k = 0; k < CHUNK; ++k) STEP(A[k]);
    RENORM();
    // tail: steps 544..574 (31 steps)
#pragma unroll
    for (int k = 0; k < 31; ++k) STEP(Bv[k]);

    if (lane == 63) {
        float DA = ((float)S2A - log2f(prev2.x)) * LN2;
        float DB = ((float)S2B - log2f(prev2.y)) * LN2;
        out[b * NFILT + fA] = DA * (1.0f / (float)T_LEN);
        out[b * NFILT + fB] = DB * (1.0f / (float)T_LEN);
    }
#undef STEP
#undef RENORM
}

extern "C" void kernel_launch(void* const* d_in, const int* in_sizes, int n_in,
                              void* d_out, int out_size, void* d_ws, size_t ws_size,
                              hipStream_t stream) {
    const float* x      = (const float*)d_in[0];
    const float* protos = (const float*)d_in[1];
    float* out          = (float*)d_out;

    dim3 grid(NBATCH * 4);   // 256 blocks; 4 waves/block = 1 wave/SIMD
    dim3 block(256);         // each wave: 2 problems (f, f+16), same b
    hipLaunchKernelGGL(dtw_kernel, grid, block, 0, stream, x, protos, out);
}